// Round 2
// baseline (311.513 us; speedup 1.0000x reference)
//
#include <hip/hip_runtime.h>
#include <stdint.h>

#define NB 64
#define SEQL 512
#define L 510
#define T 9
#define H 768
#define EMS 12           // padded emission row stride (floats): 48B, float4-aligned
#define LN2 0.6931471805599453f

__device__ __forceinline__ float rl(float v, int l) {
  return __uint_as_float(__builtin_amdgcn_readlane(__float_as_uint(v), l));
}

// ---------------- Kernel 1: emissions (+exp) = hidden[:,1:-1,:] @ W^T + bias --
__global__ __launch_bounds__(256) void emis_kernel(
    const float* __restrict__ hidden, const float* __restrict__ weight,
    const float* __restrict__ bias, float* __restrict__ em,
    float* __restrict__ eem, float* __restrict__ out) {
  __shared__ float4 wl[T * 192];  // 9 x 768 floats
  const float4* w4 = (const float4*)weight;
  for (int k = threadIdx.x; k < T * 192; k += 256) wl[k] = w4[k];
  if (blockIdx.x == 0 && threadIdx.x == 0) out[0] = 0.f;  // atomic target init
  __syncthreads();
  const int lane = threadIdx.x & 63;
  const int r = blockIdx.x * 4 + (threadIdx.x >> 6);  // row in [0, 32640)
  const int b = r / L;
  const int l = r - b * L;
  const float4* h4 = (const float4*)(hidden + ((size_t)(b * SEQL + l + 1)) * H);
  float acc[T];
#pragma unroll
  for (int t = 0; t < T; ++t) acc[t] = 0.f;
#pragma unroll
  for (int k = 0; k < 3; ++k) {
    float4 h = h4[lane + 64 * k];
#pragma unroll
    for (int t = 0; t < T; ++t) {
      float4 w = wl[t * 192 + lane + 64 * k];
      acc[t] = fmaf(h.x, w.x, fmaf(h.y, w.y, fmaf(h.z, w.z, fmaf(h.w, w.w, acc[t]))));
    }
  }
#pragma unroll
  for (int off = 32; off; off >>= 1) {
#pragma unroll
    for (int t = 0; t < T; ++t) acc[t] += __shfl_xor(acc[t], off);
  }
  if (lane == 0) {
#pragma unroll
    for (int t = 0; t < T; ++t) {
      float e = acc[t] + bias[t];
      em[(size_t)r * EMS + t] = e;
      eem[(size_t)r * EMS + t] = __expf(e);
    }
  }
}

// ---------------- Kernel 2: viterbi (exact, sequential) + den phase-1 --------
// grid = 64 viterbi blocks + 147 den-phase1 blocks; block = 64 threads.
__global__ __launch_bounds__(64) void crf_main(
    const float* __restrict__ em, const float* __restrict__ eem,
    const int* __restrict__ labels, const float* __restrict__ start_t,
    const float* __restrict__ end_t, const float* __restrict__ trans,
    float* __restrict__ PdLn, float* __restrict__ out) {
  __shared__ float s_em[L * EMS];            // 24480 B
  __shared__ float s_sc[L * 13];             // score rows, stride 13 (bank-safe)
  __shared__ int s_tag[L];
  __shared__ unsigned char s_bp[L * EMS];    // bp bytes, stride 12
  __shared__ float s_tr[81];

  const int lane = threadIdx.x;

  if (blockIdx.x < NB) {
    // ===================== VITERBI (bit-exact) ==============================
    const int b = blockIdx.x;
    const float4* g4 = (const float4*)(em + (size_t)b * L * EMS);
    float4* l4 = (float4*)s_em;
    for (int k = lane; k < L * 3; k += 64) l4[k] = g4[k];
    for (int k = lane; k < L; k += 64) s_tag[k] = labels[b * SEQL + 1 + k];
    if (lane < 81) s_tr[lane] = trans[lane];
    __syncthreads();

    const int jc = lane < 9 ? lane : 8;
    float tcol[9];
#pragma unroll
    for (int i = 0; i < 9; ++i) tcol[i] = s_tr[i * 9 + jc];

    // ---- forward max-scan (no argmax in the chain) ----
    float score = start_t[jc] + s_em[jc];
    if (lane < 9) s_sc[lane] = score;
    float em_nxt = s_em[1 * EMS + jc];
    int tg_nxt = s_tag[1];
    for (int l = 1; l < L; ++l) {
      float em_cur = em_nxt;
      int tg = tg_nxt;
      if (l < L - 1) { em_nxt = s_em[(l + 1) * EMS + jc]; tg_nxt = s_tag[l + 1]; }
      float v0 = rl(score, 0) + tcol[0];
      float v1 = rl(score, 1) + tcol[1];
      float v2 = rl(score, 2) + tcol[2];
      float v3 = rl(score, 3) + tcol[3];
      float v4 = rl(score, 4) + tcol[4];
      float v5 = rl(score, 5) + tcol[5];
      float v6 = rl(score, 6) + tcol[6];
      float v7 = rl(score, 7) + tcol[7];
      float v8 = rl(score, 8) + tcol[8];
      float m012 = fmaxf(fmaxf(v0, v1), v2);
      float m345 = fmaxf(fmaxf(v3, v4), v5);
      float m678 = fmaxf(fmaxf(v6, v7), v8);
      float mx = fmaxf(fmaxf(m012, m345), m678);
      float ns = mx + em_cur;
      score = (tg >= 0) ? ns : score;
      if (lane < 9) s_sc[l * 13 + lane] = score;
    }
    // last tag = first-index argmax of score + end
    float fv = (lane < 9) ? (score + end_t[jc]) : -1e30f;
    float f0 = rl(fv, 0), f1 = rl(fv, 1), f2 = rl(fv, 2), f3 = rl(fv, 3);
    float f4 = rl(fv, 4), f5 = rl(fv, 5), f6 = rl(fv, 6), f7 = rl(fv, 7), f8 = rl(fv, 8);
    int last = 0; float bv = f0;
    if (f1 > bv) { bv = f1; last = 1; }
    if (f2 > bv) { bv = f2; last = 2; }
    if (f3 > bv) { bv = f3; last = 3; }
    if (f4 > bv) { bv = f4; last = 4; }
    if (f5 > bv) { bv = f5; last = 5; }
    if (f6 > bv) { bv = f6; last = 6; }
    if (f7 > bv) { bv = f7; last = 7; }
    if (f8 > bv) { bv = f8; last = 8; }
    __syncthreads();

    // ---- bp extraction, parallel over l (bit-identical adds => exact) ----
    float Etr[81];
#pragma unroll
    for (int k = 0; k < 81; ++k) Etr[k] = s_tr[k];
    for (int l = 1 + lane; l < L; l += 64) {
      float sp[9];
#pragma unroll
      for (int i = 0; i < 9; ++i) sp[i] = s_sc[(l - 1) * 13 + i];
      bool msk = s_tag[l] >= 0;
#pragma unroll
      for (int j = 0; j < 9; ++j) {
        float best = sp[0] + Etr[0 * 9 + j]; int bi = 0;
#pragma unroll
        for (int i = 1; i < 9; ++i) {
          float v = sp[i] + Etr[i * 9 + j];
          if (v > best) { best = v; bi = i; }
        }
        s_bp[l * EMS + j] = (unsigned char)(msk ? bi : j);
      }
    }
    __syncthreads();

    // ---- backtrack: bpermute chase (~30 cyc/step) ----
    int tau = last;
    if (lane == 0) out[1 + (size_t)b * L + (L - 1)] = (s_tag[L - 1] >= 0) ? (float)tau : 0.f;
    int bpv_nxt = (int)s_bp[(L - 1) * EMS + jc];
    for (int l = L - 1; l >= 1; --l) {
      int bpv = bpv_nxt;
      if (l > 1) bpv_nxt = (int)s_bp[(l - 1) * EMS + jc];
      tau = __builtin_amdgcn_ds_bpermute(tau << 2, bpv);
      if (lane == 0) out[1 + (size_t)b * L + (l - 1)] = (s_tag[l - 1] >= 0) ? (float)tau : 0.f;
    }
  } else {
    // ===================== DEN PHASE 1: chunk transfer matrices =============
    const int wid = blockIdx.x - NB;           // 0..146
    const int m7 = lane / 9;                   // task-in-wave 0..7
    const int i9 = lane - m7 * 9;              // row index
    const int task = wid * 7 + (m7 < 7 ? m7 : 6);
    const bool act = (m7 < 7) && (task < 1024);
    const int ctask = act ? task : 0;
    const int b = ctask >> 4, s = ctask & 15;
    const int nt = (s == 15) ? 29 : 32;        // transitions in chunk
    const int l0 = 32 * s + 1;

    float E[81];
#pragma unroll
    for (int k = 0; k < 81; ++k) E[k] = __expf(trans[k]);

    const float* ee = eem + ((size_t)(b * L + l0)) * EMS;
    const int* lb = labels + b * SEQL + 1 + l0;

    // init with first step matrix (row i9): R[j] = E[i9][j]*e0[j] (or identity if masked)
    float4 ea = *(const float4*)(ee);
    float4 eb = *(const float4*)(ee + 4);
    float e8 = ee[8];
    bool m0 = lb[0] >= 0;
    float ec[9] = {ea.x, ea.y, ea.z, ea.w, eb.x, eb.y, eb.z, eb.w, e8};
    float R[9];
#pragma unroll
    for (int j = 0; j < 9; ++j)
      R[j] = m0 ? E[i9 * 9 + j] * ec[j] : ((i9 == j) ? 1.f : 0.f);
    int iexp = 0;

    // prefetch step 1
    float4 na = *(const float4*)(ee + EMS);
    float4 nb = *(const float4*)(ee + EMS + 4);
    float n8 = ee[EMS + 8];
    int nm = lb[1];

    for (int t = 1; t < nt; ++t) {
      float e0 = na.x, e1 = na.y, e2 = na.z, e3 = na.w;
      float e4 = nb.x, e5 = nb.y, e6 = nb.z, e7 = nb.w, e8c = n8;
      bool m = nm >= 0;
      if (t < nt - 1) {
        na = *(const float4*)(ee + (size_t)(t + 1) * EMS);
        nb = *(const float4*)(ee + (size_t)(t + 1) * EMS + 4);
        n8 = ee[(size_t)(t + 1) * EMS + 8];
        nm = lb[t + 1];
      }
      float Rn[9];
#pragma unroll
      for (int j = 0; j < 9; ++j) {
        float a = R[0] * E[0 * 9 + j];
#pragma unroll
        for (int k = 1; k < 9; ++k) a = fmaf(R[k], E[k * 9 + j], a);
        Rn[j] = a;
      }
      Rn[0] *= e0; Rn[1] *= e1; Rn[2] *= e2; Rn[3] *= e3; Rn[4] *= e4;
      Rn[5] *= e5; Rn[6] *= e6; Rn[7] *= e7; Rn[8] *= e8c;
#pragma unroll
      for (int j = 0; j < 9; ++j) R[j] = m ? Rn[j] : R[j];
      if ((t & 3) == 0) {  // power-of-2 per-row rescale (no transcendentals)
        float mx = R[0];
#pragma unroll
        for (int j = 1; j < 9; ++j) mx = fmaxf(mx, R[j]);
        int ex = (int)((__float_as_uint(mx) >> 23) & 0xff) - 127;
        iexp += ex;
        float sc = __uint_as_float((uint32_t)(127 - ex) << 23);
#pragma unroll
        for (int j = 0; j < 9; ++j) R[j] *= sc;
      }
    }
    if (act) {
      float ls = (float)iexp * LN2;
#pragma unroll
      for (int j = 0; j < 9; ++j)
        PdLn[(size_t)task * 81 + j * 9 + i9] = __logf(R[j]) + ls;
    }
  }
}

// ---------------- Kernel 3: den phase-2 (LSE compose) + numerator + out[0] ---
__global__ __launch_bounds__(64) void crf_den2(
    const float* __restrict__ em, const int* __restrict__ labels,
    const float* __restrict__ PdLn, const float* __restrict__ start_t,
    const float* __restrict__ end_t, const float* __restrict__ trans,
    float* __restrict__ out) {
  const int b = blockIdx.x;
  const int lane = threadIdx.x;

  // ---- numerator partial (parallel over l) ----
  float part = 0.f;
  for (int l = 1 + lane; l < L; l += 64) {
    int raw = labels[b * SEQL + 1 + l];
    if (raw >= 0) {
      int p = l - 1;
      while (p >= 1 && labels[b * SEQL + 1 + p] < 0) --p;
      int pt;
      if (p >= 1) pt = labels[b * SEQL + 1 + p];
      else { int r0 = labels[b * SEQL + 1]; pt = (r0 >= 0) ? r0 : 0; }
      part += trans[pt * 9 + raw] + em[((size_t)(b * L + l)) * EMS + raw];
    }
  }
#pragma unroll
  for (int off = 32; off; off >>= 1) part += __shfl_xor(part, off);

  // ---- den phase 2: 16 LSE compose steps, lanes 0..8 hold D[j] ----
  const int j = lane < 9 ? lane : 8;
  float D = start_t[j] + em[(size_t)b * L * EMS + j];
  for (int s = 0; s < 16; ++s) {
    const float* col = PdLn + ((size_t)(b * 16 + s)) * 81 + j * 9;
    float c0 = col[0], c1 = col[1], c2 = col[2], c3 = col[3], c4 = col[4];
    float c5 = col[5], c6 = col[6], c7 = col[7], c8 = col[8];
    float v0 = rl(D, 0) + c0, v1 = rl(D, 1) + c1, v2 = rl(D, 2) + c2;
    float v3 = rl(D, 3) + c3, v4 = rl(D, 4) + c4, v5 = rl(D, 5) + c5;
    float v6 = rl(D, 6) + c6, v7 = rl(D, 7) + c7, v8 = rl(D, 8) + c8;
    float mx = fmaxf(fmaxf(fmaxf(fmaxf(v0, v1), fmaxf(v2, v3)),
                           fmaxf(fmaxf(v4, v5), fmaxf(v6, v7))), v8);
    float sum = __expf(v0 - mx) + __expf(v1 - mx) + __expf(v2 - mx) +
                __expf(v3 - mx) + __expf(v4 - mx) + __expf(v5 - mx) +
                __expf(v6 - mx) + __expf(v7 - mx) + __expf(v8 - mx);
    D = mx + __logf(sum);
  }
  float fe = D + end_t[j];
  float w0 = rl(fe, 0), w1 = rl(fe, 1), w2 = rl(fe, 2), w3 = rl(fe, 3);
  float w4 = rl(fe, 4), w5 = rl(fe, 5), w6 = rl(fe, 6), w7 = rl(fe, 7), w8 = rl(fe, 8);
  float mx = fmaxf(fmaxf(fmaxf(fmaxf(w0, w1), fmaxf(w2, w3)),
                         fmaxf(fmaxf(w4, w5), fmaxf(w6, w7))), w8);
  float den = mx + __logf(__expf(w0 - mx) + __expf(w1 - mx) + __expf(w2 - mx) +
                          __expf(w3 - mx) + __expf(w4 - mx) + __expf(w5 - mx) +
                          __expf(w6 - mx) + __expf(w7 - mx) + __expf(w8 - mx));

  if (lane == 0) {
    int r0 = labels[b * SEQL + 1];
    int tag0 = (r0 >= 0) ? r0 : 0;
    float score0 = start_t[tag0] + em[(size_t)b * L * EMS + tag0];
    int q = L - 1;
    while (q >= 1 && labels[b * SEQL + 1 + q] < 0) --q;
    int lastt = (q >= 1) ? labels[b * SEQL + 1 + q] : tag0;
    float numerator = score0 + part + end_t[lastt];
    atomicAdd(out, den - numerator);  // out[0] = -sum(llh)
  }
}

extern "C" void kernel_launch(void* const* d_in, const int* in_sizes, int n_in,
                              void* d_out, int out_size, void* d_ws, size_t ws_size,
                              hipStream_t stream) {
  const float* hidden  = (const float*)d_in[0];
  const int*   labels  = (const int*)d_in[1];
  const float* weight  = (const float*)d_in[2];
  const float* bias    = (const float*)d_in[3];
  const float* start_t = (const float*)d_in[4];
  const float* end_t   = (const float*)d_in[5];
  const float* trans   = (const float*)d_in[6];
  float* out = (float*)d_out;

  float* em   = (float*)d_ws;                       // 64*510*12 = 391680 f
  float* eem  = em + (size_t)NB * L * EMS;          // 391680 f
  float* PdLn = eem + (size_t)NB * L * EMS;         // 1024*81 = 82944 f

  emis_kernel<<<NB * L / 4, 256, 0, stream>>>(hidden, weight, bias, em, eem, out);
  crf_main<<<NB + 147, 64, 0, stream>>>(em, eem, labels, start_t, end_t, trans, PdLn, out);
  crf_den2<<<NB, 64, 0, stream>>>(em, labels, PdLn, start_t, end_t, trans, out);
}

// Round 3
// 224.572 us; speedup vs baseline: 1.3871x; 1.3871x over previous
//
#include <hip/hip_runtime.h>
#include <stdint.h>

#define NB 64
#define SEQL 512
#define L 510
#define T 9
#define H 768
#define EMS 12           // padded emission row stride (floats)
#define LN2 0.6931471805599453f

__device__ __forceinline__ float rl(float v, int l) {
  return __uint_as_float(__builtin_amdgcn_readlane(__float_as_uint(v), l));
}

// ---------------- K1: emissions = hidden[:,1:-1,:] @ W^T + bias (+exp) -------
// 64 rows/block (amortizes the 27.6KB weight staging), row-pairs share w reads.
__global__ __launch_bounds__(256) void emis_kernel(
    const float* __restrict__ hidden, const float* __restrict__ weight,
    const float* __restrict__ bias, float* __restrict__ em,
    float* __restrict__ eem, float* __restrict__ out) {
  __shared__ float4 wl[T * 192];  // 9 x 768 floats
  const float4* w4 = (const float4*)weight;
  for (int k = threadIdx.x; k < T * 192; k += 256) wl[k] = w4[k];
  if (blockIdx.x == 0 && threadIdx.x == 0) out[0] = 0.f;  // atomic target init
  __syncthreads();
  const int lane = threadIdx.x & 63;
  const int wv = threadIdx.x >> 6;
  const int base = blockIdx.x * 64 + wv * 16;
#pragma unroll 1
  for (int pr = 0; pr < 8; ++pr) {
    const int r0 = base + pr * 2, r1 = r0 + 1;
    const int b0 = r0 / L, p0 = r0 - b0 * L;
    const int b1 = r1 / L, p1 = r1 - b1 * L;
    const float4* h0 = (const float4*)(hidden + ((size_t)(b0 * SEQL + p0 + 1)) * H);
    const float4* h1 = (const float4*)(hidden + ((size_t)(b1 * SEQL + p1 + 1)) * H);
    float4 ha[3], hb[3];
#pragma unroll
    for (int k = 0; k < 3; ++k) { ha[k] = h0[lane + 64 * k]; hb[k] = h1[lane + 64 * k]; }
    float a0[T], a1[T];
#pragma unroll
    for (int t = 0; t < T; ++t) { a0[t] = 0.f; a1[t] = 0.f; }
#pragma unroll
    for (int t = 0; t < T; ++t) {
#pragma unroll
      for (int k = 0; k < 3; ++k) {
        float4 w = wl[t * 192 + lane + 64 * k];  // shared by both rows
        a0[t] = fmaf(ha[k].x, w.x, fmaf(ha[k].y, w.y, fmaf(ha[k].z, w.z, fmaf(ha[k].w, w.w, a0[t]))));
        a1[t] = fmaf(hb[k].x, w.x, fmaf(hb[k].y, w.y, fmaf(hb[k].z, w.z, fmaf(hb[k].w, w.w, a1[t]))));
      }
    }
#pragma unroll
    for (int off = 32; off; off >>= 1) {
#pragma unroll
      for (int t = 0; t < T; ++t) {
        a0[t] += __shfl_xor(a0[t], off);
        a1[t] += __shfl_xor(a1[t], off);
      }
    }
    if (lane < 2) {
      const int rr = lane ? r1 : r0;
      float* eo = em + (size_t)rr * EMS;
      float* xo = eem + (size_t)rr * EMS;
#pragma unroll
      for (int t = 0; t < T; ++t) {
        float v = (lane ? a1[t] : a0[t]) + bias[t];
        eo[t] = v;
        xo[t] = __expf(v);
      }
    }
  }
}

// ---------------- K2: per-chunk transfer matrices (den linear + viterbi maxplus)
// blocks [0,147): den; [147,294): viterbi. 7 tasks/wave, lane = task*9+row.
__global__ __launch_bounds__(64) void chunk_kernel(
    const float* __restrict__ em, const float* __restrict__ eem,
    const float* __restrict__ trans, float* __restrict__ PdLn,
    float* __restrict__ Mv) {
  const int lane = threadIdx.x;
  const int m7 = lane / 9;
  const int i9 = lane - m7 * 9;
  const bool isden = blockIdx.x < 147;
  const int wid = isden ? blockIdx.x : blockIdx.x - 147;
  const int rtask = wid * 7 + (m7 < 7 ? m7 : 6);
  const bool act = (m7 < 7) && (rtask < 1024);
  const int task = act ? rtask : 0;
  const int b = task >> 4, s = task & 15;
  const int nt = (s == 15) ? 29 : 32;
  const int l0 = 32 * s + 1;

  if (isden) {
    float E[81];
#pragma unroll
    for (int k = 0; k < 81; ++k) E[k] = __expf(trans[k]);
    const float* ee = eem + ((size_t)(b * L + l0)) * EMS;
    float4 ea = *(const float4*)(ee);
    float4 eb = *(const float4*)(ee + 4);
    float e8 = ee[8];
    float ec[9] = {ea.x, ea.y, ea.z, ea.w, eb.x, eb.y, eb.z, eb.w, e8};
    float R[9];
#pragma unroll
    for (int j = 0; j < 9; ++j) R[j] = E[i9 * 9 + j] * ec[j];
    int iexp = 0;
    float4 na = *(const float4*)(ee + EMS);
    float4 nb = *(const float4*)(ee + EMS + 4);
    float n8 = ee[EMS + 8];
    for (int t = 1; t < nt; ++t) {
      float e0 = na.x, e1 = na.y, e2 = na.z, e3 = na.w;
      float e4 = nb.x, e5 = nb.y, e6 = nb.z, e7 = nb.w, e8c = n8;
      if (t < nt - 1) {
        na = *(const float4*)(ee + (size_t)(t + 1) * EMS);
        nb = *(const float4*)(ee + (size_t)(t + 1) * EMS + 4);
        n8 = ee[(size_t)(t + 1) * EMS + 8];
      }
      float Rn[9];
#pragma unroll
      for (int j = 0; j < 9; ++j) {
        float a = R[0] * E[0 * 9 + j];
#pragma unroll
        for (int k = 1; k < 9; ++k) a = fmaf(R[k], E[k * 9 + j], a);
        Rn[j] = a;
      }
      R[0] = Rn[0] * e0; R[1] = Rn[1] * e1; R[2] = Rn[2] * e2;
      R[3] = Rn[3] * e3; R[4] = Rn[4] * e4; R[5] = Rn[5] * e5;
      R[6] = Rn[6] * e6; R[7] = Rn[7] * e7; R[8] = Rn[8] * e8c;
      if ((t & 3) == 0) {  // power-of-2 rescale
        float mx = R[0];
#pragma unroll
        for (int j = 1; j < 9; ++j) mx = fmaxf(mx, R[j]);
        int ex = (int)((__float_as_uint(mx) >> 23) & 0xff) - 127;
        iexp += ex;
        float sc = __uint_as_float((uint32_t)(127 - ex) << 23);
#pragma unroll
        for (int j = 0; j < 9; ++j) R[j] *= sc;
      }
    }
    if (act) {
      float ls = (float)iexp * LN2;
#pragma unroll
      for (int j = 0; j < 9; ++j)
        PdLn[(size_t)task * 81 + j * 9 + i9] = __logf(R[j]) + ls;
    }
  } else {
    float t_[81];
#pragma unroll
    for (int k = 0; k < 81; ++k) t_[k] = trans[k];
    const float* ep = em + ((size_t)(b * L + l0)) * EMS;
    float4 ea = *(const float4*)(ep);
    float4 eb = *(const float4*)(ep + 4);
    float e8 = ep[8];
    float ec[9] = {ea.x, ea.y, ea.z, ea.w, eb.x, eb.y, eb.z, eb.w, e8};
    float V[9];
#pragma unroll
    for (int j = 0; j < 9; ++j) V[j] = t_[i9 * 9 + j] + ec[j];
    float4 na = *(const float4*)(ep + EMS);
    float4 nb = *(const float4*)(ep + EMS + 4);
    float n8 = ep[EMS + 8];
    for (int t = 1; t < nt; ++t) {
      float e[9] = {na.x, na.y, na.z, na.w, nb.x, nb.y, nb.z, nb.w, n8};
      if (t < nt - 1) {
        na = *(const float4*)(ep + (size_t)(t + 1) * EMS);
        nb = *(const float4*)(ep + (size_t)(t + 1) * EMS + 4);
        n8 = ep[(size_t)(t + 1) * EMS + 8];
      }
      float Vn[9];
#pragma unroll
      for (int j = 0; j < 9; ++j) {
        float m = V[0] + t_[0 * 9 + j];
#pragma unroll
        for (int k = 1; k < 9; ++k) m = fmaxf(m, V[k] + t_[k * 9 + j]);
        Vn[j] = m + e[j];
      }
#pragma unroll
      for (int j = 0; j < 9; ++j) V[j] = Vn[j];
    }
    if (act) {
#pragma unroll
      for (int j = 0; j < 9; ++j)
        Mv[(size_t)task * 81 + j * 9 + i9] = V[j];  // column-major [j][i]
    }
  }
}

// ---------------- K3: per-batch compose (den LSE + viterbi boundary + chase) -
__global__ __launch_bounds__(64) void compose_kernel(
    const float* __restrict__ em, const int* __restrict__ labels,
    const float* __restrict__ PdLn, const float* __restrict__ Mv,
    const float* __restrict__ start_t, const float* __restrict__ end_t,
    const float* __restrict__ trans, unsigned char* __restrict__ chosen,
    float* __restrict__ out) {
  __shared__ float s_pd[16 * 81];
  __shared__ float s_mv[16 * 81];
  __shared__ float s_A[17 * 9];
  __shared__ float s_t[81];
  __shared__ int s_lab[L];
  const int b = blockIdx.x;
  const int lane = threadIdx.x;
  for (int k = lane; k < 16 * 81; k += 64) {
    s_pd[k] = PdLn[(size_t)b * 16 * 81 + k];
    s_mv[k] = Mv[(size_t)b * 16 * 81 + k];
  }
  for (int k = lane; k < 81; k += 64) s_t[k] = trans[k];
  for (int k = lane; k < L; k += 64) s_lab[k] = labels[b * SEQL + 1 + k];
  __syncthreads();

  const int jj = lane < 9 ? lane : 8;

  // ---- numerator (mask all-true): parallel over l ----
  float part = 0.f;
  for (int l = lane; l < L; l += 64) {
    int tg = s_lab[l];
    float e = em[((size_t)(b * L + l)) * EMS + tg];
    if (l == 0) part += start_t[tg] + e;
    else part += s_t[s_lab[l - 1] * 9 + tg] + e;
    if (l == L - 1) part += end_t[tg];
  }
#pragma unroll
  for (int off = 32; off; off >>= 1) part += __shfl_xor(part, off);

  // ---- denominator: 16 LSE compose steps, lane j ----
  float D = start_t[jj] + em[(size_t)b * L * EMS + jj];
  for (int s = 0; s < 16; ++s) {
    const float* col = &s_pd[s * 81 + jj * 9];
    float v0 = rl(D, 0) + col[0], v1 = rl(D, 1) + col[1], v2 = rl(D, 2) + col[2];
    float v3 = rl(D, 3) + col[3], v4 = rl(D, 4) + col[4], v5 = rl(D, 5) + col[5];
    float v6 = rl(D, 6) + col[6], v7 = rl(D, 7) + col[7], v8 = rl(D, 8) + col[8];
    float mx = fmaxf(fmaxf(fmaxf(fmaxf(v0, v1), fmaxf(v2, v3)),
                           fmaxf(fmaxf(v4, v5), fmaxf(v6, v7))), v8);
    float sum = __expf(v0 - mx) + __expf(v1 - mx) + __expf(v2 - mx) +
                __expf(v3 - mx) + __expf(v4 - mx) + __expf(v5 - mx) +
                __expf(v6 - mx) + __expf(v7 - mx) + __expf(v8 - mx);
    D = mx + __logf(sum);
  }
  float fe = D + end_t[jj];
  float w0 = rl(fe, 0), w1 = rl(fe, 1), w2 = rl(fe, 2), w3 = rl(fe, 3);
  float w4 = rl(fe, 4), w5 = rl(fe, 5), w6 = rl(fe, 6), w7 = rl(fe, 7), w8 = rl(fe, 8);
  float mx = fmaxf(fmaxf(fmaxf(fmaxf(w0, w1), fmaxf(w2, w3)),
                         fmaxf(fmaxf(w4, w5), fmaxf(w6, w7))), w8);
  float den = mx + __logf(__expf(w0 - mx) + __expf(w1 - mx) + __expf(w2 - mx) +
                          __expf(w3 - mx) + __expf(w4 - mx) + __expf(w5 - mx) +
                          __expf(w6 - mx) + __expf(w7 - mx) + __expf(w8 - mx));
  if (lane == 0) atomicAdd(out, den - part);  // out[0] = -sum(llh)

  // ---- viterbi boundary alphas (max-plus compose), lane j ----
  float A = start_t[jj] + em[(size_t)b * L * EMS + jj];
  if (lane < 9) s_A[lane] = A;
  for (int s = 0; s < 16; ++s) {
    const float* col = &s_mv[s * 81 + jj * 9];
    float u0 = rl(A, 0) + col[0], u1 = rl(A, 1) + col[1], u2 = rl(A, 2) + col[2];
    float u3 = rl(A, 3) + col[3], u4 = rl(A, 4) + col[4], u5 = rl(A, 5) + col[5];
    float u6 = rl(A, 6) + col[6], u7 = rl(A, 7) + col[7], u8 = rl(A, 8) + col[8];
    A = fmaxf(fmaxf(fmaxf(fmaxf(u0, u1), fmaxf(u2, u3)),
                    fmaxf(fmaxf(u4, u5), fmaxf(u6, u7))), u8);
    if (lane < 9) s_A[(s + 1) * 9 + lane] = A;
  }
  // last tag: first-index argmax of A + end
  float fv = A + end_t[jj];
  int j = 0;
  {
    float bv = rl(fv, 0);
#pragma unroll
    for (int i = 1; i < 9; ++i) { float v = rl(fv, i); if (v > bv) { bv = v; j = i; } }
  }
  // ---- chunk-level backward chase ----
  for (int s = 15; s >= 0; --s) {
    float val = s_A[s * 9 + jj] + s_mv[s * 81 + j * 9 + jj];  // lane = entry state i
    int ii = 0;
    float bb = rl(val, 0);
#pragma unroll
    for (int i = 1; i < 9; ++i) { float v = rl(val, i); if (v > bb) { bb = v; ii = i; } }
    if (lane == 0) {
      chosen[(b * 16 + s) * 2] = (unsigned char)ii;
      chosen[(b * 16 + s) * 2 + 1] = (unsigned char)j;
    }
    j = ii;
  }
  if (lane == 0) out[1 + (size_t)b * L] = (float)j;  // tag at position 0
}

// ---------------- K4: per-chunk path re-run (chosen row) + backtrack + emit --
__global__ __launch_bounds__(64) void path_kernel(
    const float* __restrict__ em, const float* __restrict__ trans,
    const unsigned char* __restrict__ chosen, float* __restrict__ out) {
  __shared__ float s_t[81];
  __shared__ uint32_t s_bp[32][64][2];  // [q][lane][word], 16 KB
  const int lane = threadIdx.x;
  for (int k = lane; k < 81; k += 64) s_t[k] = trans[k];
  __syncthreads();
  const int task = blockIdx.x * 64 + lane;
  const int b = task >> 4, s = task & 15;
  const int nt = (s == 15) ? 29 : 32;
  const int l0 = 32 * s + 1;
  const int i0 = chosen[task * 2];
  const int jF = chosen[task * 2 + 1];
  float t_[81];
#pragma unroll
  for (int k = 0; k < 81; ++k) t_[k] = trans[k];  // uniform -> scalar loads
  const float* ep = em + ((size_t)(b * L + l0)) * EMS;
  float a[9];
  {
    float4 ea = *(const float4*)(ep);
    float4 eb = *(const float4*)(ep + 4);
    float e8 = ep[8];
    float e[9] = {ea.x, ea.y, ea.z, ea.w, eb.x, eb.y, eb.z, eb.w, e8};
#pragma unroll
    for (int jx = 0; jx < 9; ++jx) a[jx] = s_t[i0 * 9 + jx] + e[jx];
  }
  for (int q = 1; q < nt; ++q) {
    float4 na = *(const float4*)(ep + (size_t)q * EMS);
    float4 nb = *(const float4*)(ep + (size_t)q * EMS + 4);
    float n8 = ep[(size_t)q * EMS + 8];
    float e[9] = {na.x, na.y, na.z, na.w, nb.x, nb.y, nb.z, nb.w, n8};
    uint32_t pk0 = 0, pk1 = 0;
    float an[9];
#pragma unroll
    for (int jx = 0; jx < 9; ++jx) {
      float best = a[0] + t_[0 * 9 + jx];
      int bi = 0;
#pragma unroll
      for (int k = 1; k < 9; ++k) {
        float v = a[k] + t_[k * 9 + jx];
        if (v > best) { best = v; bi = k; }
      }
      an[jx] = best + e[jx];
      if (jx < 8) pk0 |= ((uint32_t)bi) << (4 * jx);
      else pk1 = (uint32_t)bi;
    }
    s_bp[q][lane][0] = pk0;
    s_bp[q][lane][1] = pk1;
#pragma unroll
    for (int jx = 0; jx < 9; ++jx) a[jx] = an[jx];
  }
  // backtrack own chunk, write tags
  int cur = jF;
  float* orow = out + 1 + (size_t)b * L + l0;
  for (int q = nt - 1; q >= 1; --q) {
    orow[q] = (float)cur;
    uint32_t w = s_bp[q][lane][cur >> 3];
    cur = (int)((w >> ((cur & 7) * 4)) & 15u);
  }
  orow[0] = (float)cur;
}

extern "C" void kernel_launch(void* const* d_in, const int* in_sizes, int n_in,
                              void* d_out, int out_size, void* d_ws, size_t ws_size,
                              hipStream_t stream) {
  const float* hidden  = (const float*)d_in[0];
  const int*   labels  = (const int*)d_in[1];
  const float* weight  = (const float*)d_in[2];
  const float* bias    = (const float*)d_in[3];
  const float* start_t = (const float*)d_in[4];
  const float* end_t   = (const float*)d_in[5];
  const float* trans   = (const float*)d_in[6];
  float* out = (float*)d_out;

  float* em   = (float*)d_ws;                        // 391680 f
  float* eem  = em + (size_t)NB * L * EMS;           // 391680 f
  float* PdLn = eem + (size_t)NB * L * EMS;          // 82944 f
  float* Mv   = PdLn + (size_t)1024 * 81;            // 82944 f
  unsigned char* chosen = (unsigned char*)(Mv + (size_t)1024 * 81);  // 2048 B

  emis_kernel<<<510, 256, 0, stream>>>(hidden, weight, bias, em, eem, out);
  chunk_kernel<<<294, 64, 0, stream>>>(em, eem, trans, PdLn, Mv);
  compose_kernel<<<NB, 64, 0, stream>>>(em, labels, PdLn, Mv, start_t, end_t,
                                        trans, chosen, out);
  path_kernel<<<16, 64, 0, stream>>>(em, trans, chosen, out);
}